// Round 2
// 722.728 us; speedup vs baseline: 1.0164x; 1.0164x over previous
//
#include <hip/hip_runtime.h>

// Fused downsample-GEMV + per-block LSTM scan.
// x: (B=64, C=2, T=128, 96, 96) f32, channel 0 only.
// W_ih (3,3,4,1024); W_hh/b_ih/b_hh (3,3,4); out: (T=128, B=64, 3, 3) f32.
//
// One wave per (b, cell): 576 single-wave blocks. Each wave streams its
// cell's 32x32 block of each t-slab (4 KB/t, depth-2 prefetch via 4 rotating
// register buffers, unroll-4 so all indexing is static -> no scratch), does
// the 4-gate dot product across 64 lanes (64 FMA/t), reduces with the
// gate-interleaved 7-shuffle fold, gathers all 4 gate totals to every lane
// (3 shuffles + selects), and advances (h, c) lane-redundantly in registers.
// No workspace, no second kernel, no xg round-trip.

#define T_LEN 128
#define B_SZ  64
#define NC    9
#define H_SZ  96
#define V_SZ  1024
#define SLAB  (H_SZ * H_SZ)

__device__ __forceinline__ float fsig(float xx) {
    return __builtin_amdgcn_rcpf(1.f + __expf(-xx));   // ~1e-6 abs err, tol-safe
}
__device__ __forceinline__ float ftanh(float xx) {
    // tanh(x) = 1 - 2/(1 + e^{2x}); exp->inf / ->0 saturate correctly via rcp.
    return fmaf(-2.f, __builtin_amdgcn_rcpf(1.f + __expf(2.f * xx)), 1.f);
}

__global__ __launch_bounds__(64) void fused_lstm_kernel(
    const float* __restrict__ x,
    const float* __restrict__ W_ih,
    const float* __restrict__ W_hh,
    const float* __restrict__ b_ih,
    const float* __restrict__ b_hh,
    float* __restrict__ out)          // [T][B*NC]
{
    const int lane = threadIdx.x;      // 0..63
    const int bc   = blockIdx.x;       // 0..575 = b*9 + cell
    const int cell = bc % 9;
    const int b    = bc / 9;
    const int i = cell / 3, j = cell % 3;

    // Weights in registers: wf[k][g] = W_ih[cell][g][k*256 + lane*4 .. +3]
    float4 wf[4][4];
    const float* wbase = W_ih + (size_t)cell * 4 * V_SZ;
    #pragma unroll
    for (int k = 0; k < 4; ++k) {
        const int v = k * 256 + lane * 4;
        #pragma unroll
        for (int g = 0; g < 4; ++g)
            wf[k][g] = *(const float4*)(wbase + g * V_SZ + v);
    }
    const float4 wh = *(const float4*)(W_hh + cell * 4);
    const float4 bi = *(const float4*)(b_ih + cell * 4);
    const float4 bh = *(const float4*)(b_hh + cell * 4);
    const float bx = bi.x + bh.x, by2 = bi.y + bh.y;
    const float bz = bi.z + bh.z, bw  = bi.w + bh.w;

    // Lane's v-range maps to block row p = k*8 + (lane>>3), cols q0..q0+3.
    const int p0 = lane >> 3;
    const int q0 = (lane & 7) * 4;
    const float* slab0 = x + (size_t)(b * 2) * T_LEN * SLAB
                           + (i * 32) * H_SZ + j * 32 + q0;

    const bool pb0 = (lane & 1) != 0;
    const bool pb1 = (lane & 2) != 0;

    float h = 0.f, c = 0.f;
    float4 P0[4], P1[4], P2[4], P3[4];

    auto LOADT = [&](float4 (&buf)[4], int tt) {
        const float* sp = slab0 + (size_t)tt * SLAB;
        #pragma unroll
        for (int k = 0; k < 4; ++k)
            buf[k] = *(const float4*)(sp + (k * 8 + p0) * H_SZ);
    };

    auto STEPT = [&](const float4 (&xv)[4], int t) {
        float a0 = 0.f, a1 = 0.f, a2 = 0.f, a3 = 0.f;
        #pragma unroll
        for (int k = 0; k < 4; ++k) {
            const float4 v = xv[k];
            a0 = fmaf(v.x, wf[k][0].x, fmaf(v.y, wf[k][0].y, fmaf(v.z, wf[k][0].z, fmaf(v.w, wf[k][0].w, a0))));
            a1 = fmaf(v.x, wf[k][1].x, fmaf(v.y, wf[k][1].y, fmaf(v.z, wf[k][1].z, fmaf(v.w, wf[k][1].w, a1))));
            a2 = fmaf(v.x, wf[k][2].x, fmaf(v.y, wf[k][2].y, fmaf(v.z, wf[k][2].z, fmaf(v.w, wf[k][2].w, a2))));
            a3 = fmaf(v.x, wf[k][3].x, fmaf(v.y, wf[k][3].y, fmaf(v.z, wf[k][3].z, fmaf(v.w, wf[k][3].w, a3))));
        }
        // Gate-interleaved fold: after stage 2, s = gate (lane&3), quad-summed.
        float y01 = pb0 ? a0 : a1;
        float a01 = (pb0 ? a1 : a0) + __shfl_xor(y01, 1, 64);
        float y23 = pb0 ? a2 : a3;
        float a23 = (pb0 ? a3 : a2) + __shfl_xor(y23, 1, 64);
        float ys = pb1 ? a01 : a23;
        float s  = (pb1 ? a23 : a01) + __shfl_xor(ys, 2, 64);
        s += __shfl_xor(s, 4, 64);
        s += __shfl_xor(s, 8, 64);
        s += __shfl_xor(s, 16, 64);
        s += __shfl_xor(s, 32, 64);
        // Every lane now has the full-wave total for gate (lane&3).
        // Gather the other three gates: y1 = ^1, y2 = ^2, y3 = ^3.
        const float y1 = __shfl_xor(s, 1, 64);
        const float y2 = __shfl_xor(s, 2, 64);
        const float y3 = __shfl_xor(y1, 2, 64);
        const float G0 = pb1 ? (pb0 ? y3 : y2) : (pb0 ? y1 : s);
        const float G1 = pb1 ? (pb0 ? y2 : y3) : (pb0 ? s : y1);
        const float G2 = pb1 ? (pb0 ? y1 : s) : (pb0 ? y3 : y2);
        const float G3 = pb1 ? (pb0 ? s : y1) : (pb0 ? y2 : y3);

        // LSTM step, lane-redundant (all lanes hold identical h, c).
        const float gi = fmaf(wh.x, h, G0 + bx);
        const float gf = fmaf(wh.y, h, G1 + by2);
        const float gz = fmaf(wh.z, h, G2 + bz);
        const float go = fmaf(wh.w, h, G3 + bw);
        const float ii = fsig(gi);
        const float ff = fsig(gf);
        const float gt = ftanh(gz);
        const float oo = fsig(go);
        c = fmaf(ff, c, ii * gt);
        h = oo * ftanh(c);
        if (lane == 0) out[(size_t)t * (B_SZ * NC) + bc] = h;
    };

    // Depth-2 software pipeline, unroll-4 so buffer indices stay static.
    LOADT(P0, 0);
    LOADT(P1, 1);
    for (int t = 0; t < T_LEN; t += 4) {
        if (t + 2 < T_LEN) LOADT(P2, t + 2);
        STEPT(P0, t);
        if (t + 3 < T_LEN) LOADT(P3, t + 3);
        STEPT(P1, t + 1);
        if (t + 4 < T_LEN) LOADT(P0, t + 4);
        STEPT(P2, t + 2);
        if (t + 5 < T_LEN) LOADT(P1, t + 5);
        STEPT(P3, t + 3);
    }
}

extern "C" void kernel_launch(void* const* d_in, const int* in_sizes, int n_in,
                              void* d_out, int out_size, void* d_ws, size_t ws_size,
                              hipStream_t stream) {
    const float* x    = (const float*)d_in[0];
    const float* W_ih = (const float*)d_in[1];
    const float* W_hh = (const float*)d_in[2];
    const float* b_ih = (const float*)d_in[3];
    const float* b_hh = (const float*)d_in[4];
    float* out = (float*)d_out;

    (void)d_ws; (void)ws_size;   // no workspace needed anymore

    fused_lstm_kernel<<<dim3(B_SZ * NC), dim3(64), 0, stream>>>(
        x, W_ih, W_hh, b_ih, b_hh, out);
}